// Round 12
// baseline (85.654 us; speedup 1.0000x reference)
//
#include <hip/hip_runtime.h>

#define LN_EPS 1e-5f

typedef __attribute__((ext_vector_type(8))) short s16x8;
typedef __attribute__((ext_vector_type(4))) float f32x4;
typedef long long i64b;

__device__ inline unsigned int pk_bf16(float a, float b) {
    unsigned ua = __builtin_bit_cast(unsigned, a);
    unsigned ub = __builtin_bit_cast(unsigned, b);
    ua += 0x7fffu + ((ua >> 16) & 1u);
    ub += 0x7fffu + ((ub >> 16) & 1u);
    return (ua >> 16) | (ub & 0xffff0000u);
}
__device__ inline float bf2f(unsigned short h) {
    unsigned u = ((unsigned)h) << 16;
    return __builtin_bit_cast(float, u);
}
__device__ inline unsigned pk2_fp8(float a, float b) {   // 2 fp8 e4m3 in bits[15:0]
    return (unsigned)__builtin_amdgcn_cvt_pk_fp8_f32(a, b, 0, false) & 0xffffu;
}
__device__ inline unsigned char cv_fp8(float a) {
    return (unsigned char)((unsigned)__builtin_amdgcn_cvt_pk_fp8_f32(a, 0.f, 0, false) & 0xffu);
}
__device__ inline void gl_lds16(const void* g, void* l) {
    __builtin_amdgcn_global_load_lds((const __attribute__((address_space(1))) void*)g,
                                     (__attribute__((address_space(3))) void*)l, 16, 0, 0);
}

// ---------------- K1: merged scan + degree + amc(fp8) | xb bf16 + agg8-padded | W->W8 ----------------
// Valid rows recompute the per-batch prefix scan in-block (pm row is L2-hot);
// the rloc==0 block of each batch additionally writes idx + cnt.
__global__ __launch_bounds__(256) void k_degxb(const float* __restrict__ adj,
                                               const int* __restrict__ pm,
                                               const float* __restrict__ ew,
                                               const float* __restrict__ W,
                                               int* __restrict__ cnt,
                                               unsigned short* __restrict__ idx,
                                               float* __restrict__ dis_o,
                                               float* __restrict__ rs,
                                               float* __restrict__ rself,
                                               unsigned char* __restrict__ amc8,
                                               const float* __restrict__ x,
                                               unsigned short* __restrict__ xb,
                                               unsigned char* __restrict__ agg8,
                                               unsigned char* __restrict__ W8,
                                               int L, int nd, int nx) {
    const int D = 512;
    int bid = blockIdx.x;
    int t = threadIdx.x;
    float e = ew[0];
    if (bid >= nd) {
        int sub = bid - nd;
        if (sub >= nx) {                // W -> fp8 (64 blocks x 256 thr x 16 elems)
            int i = ((sub - nx) * 256 + t) * 16;
            uint4 o;
            float4 v0 = *(const float4*)(W + i);
            float4 v1 = *(const float4*)(W + i + 4);
            float4 v2 = *(const float4*)(W + i + 8);
            float4 v3 = *(const float4*)(W + i + 12);
            o.x = pk2_fp8(v0.x, v0.y) | (pk2_fp8(v0.z, v0.w) << 16);
            o.y = pk2_fp8(v1.x, v1.y) | (pk2_fp8(v1.z, v1.w) << 16);
            o.z = pk2_fp8(v2.x, v2.y) | (pk2_fp8(v2.z, v2.w) << 16);
            o.w = pk2_fp8(v3.x, v3.y) | (pk2_fp8(v3.z, v3.w) << 16);
            *(uint4*)(W8 + i) = o;
            return;
        }
        // xb = bf16(x); agg8 = fp8(e*x) for padded rows
        int gid = sub * 256 + t;
        int row = gid >> 6;
        int co = (gid & 63) << 3;
        const float* xp = x + (size_t)row * D + co;
        float4 v0 = *(const float4*)(xp);
        float4 v1 = *(const float4*)(xp + 4);
        uint4 o;
        o.x = pk_bf16(v0.x, v0.y);
        o.y = pk_bf16(v0.z, v0.w);
        o.z = pk_bf16(v1.x, v1.y);
        o.w = pk_bf16(v1.z, v1.w);
        *(uint4*)(xb + (size_t)row * D + co) = o;
        if (pm[row] != 0) {
            uint2 oa;
            oa.x = pk2_fp8(e * v0.x, e * v0.y) | (pk2_fp8(e * v0.z, e * v0.w) << 16);
            oa.y = pk2_fp8(e * v1.x, e * v1.y) | (pk2_fp8(e * v1.z, e * v1.w) << 16);
            *(uint2*)(agg8 + (size_t)row * D + co) = oa;
        }
        return;
    }
    // degree + compacted fp8 adjacency row (valid rows only)
    int row = bid;
    int b = row / L;
    int i = row - b * L;
    const int* pmb = pm + (size_t)b * L;
    if (pmb[i] != 0) {                  // padded row: deg = 1
        if (t == 0) { dis_o[row] = 1.f; rs[row] = 0.f; rself[row] = e; }
        return;
    }
    __shared__ __align__(16) unsigned char ls8[2048 + 16];
    __shared__ int ps[256];
    __shared__ float wsum[4];
    __shared__ int rloc_sh;
    const float* arow = adj + (size_t)row * L;

    int j0 = t * 8;
    int4 p0 = *(const int4*)(pmb + j0);
    int4 p1 = *(const int4*)(pmb + j0 + 4);
    int v[8];
    v[0] = (p0.x == 0); v[1] = (p0.y == 0); v[2] = (p0.z == 0); v[3] = (p0.w == 0);
    v[4] = (p1.x == 0); v[5] = (p1.y == 0); v[6] = (p1.z == 0); v[7] = (p1.w == 0);
    int s8 = v[0] + v[1] + v[2] + v[3] + v[4] + v[5] + v[6] + v[7];
    ps[t] = s8;
    __syncthreads();
    for (int off = 1; off < 256; off <<= 1) {
        int val = (t >= off) ? ps[t - off] : 0;
        __syncthreads();
        ps[t] += val;
        __syncthreads();
    }
    int base = ps[t] - s8;              // exclusive prefix of this 8-chunk
    int cb = ps[255];                   // cnt for this batch
    int kcap = (cb + 63) & ~63;
    if (t == (i >> 3)) {                // thread holding element i computes rloc
        int c = ps[t] - s8;
        int ii = i & 7;
        #pragma unroll
        for (int k = 0; k < 8; ++k) if (k < ii) c += v[k];
        rloc_sh = c;
    }

    // zero pad tail of staged row
    for (int k = cb + t; k < kcap; k += 256) ls8[k] = 0;

    float4 a0 = *(const float4*)(arow + j0);
    float4 a1 = *(const float4*)(arow + j0 + 4);
    float m[8];
    m[0] = v[0] ? a0.x : 0.f;
    m[1] = v[1] ? a0.y : 0.f;
    m[2] = v[2] ? a0.z : 0.f;
    m[3] = v[3] ? a0.w : 0.f;
    m[4] = v[4] ? a1.x : 0.f;
    m[5] = v[5] ? a1.y : 0.f;
    m[6] = v[6] ? a1.z : 0.f;
    m[7] = v[7] ? a1.w : 0.f;
    float s = ((m[0] + m[1]) + (m[2] + m[3])) + ((m[4] + m[5]) + (m[6] + m[7]));
    {
        int pc = base;
        #pragma unroll
        for (int k = 0; k < 8; ++k)
            if (v[k]) { ls8[pc] = cv_fp8(m[k]); pc++; }
    }

    #pragma unroll
    for (int off = 32; off; off >>= 1) s += __shfl_down(s, off);
    if ((t & 63) == 0) wsum[t >> 6] = s;
    __syncthreads();

    int rloc = rloc_sh;
    unsigned char* amrow = amc8 + ((size_t)b * L + rloc) * L;
    if (j0 < kcap) *(uint2*)(amrow + j0) = *(const uint2*)(ls8 + j0);

    if (rloc == 0) {                    // first valid row of batch writes idx + cnt
        unsigned short* idxb = idx + (size_t)b * L;
        int bb = base;
        #pragma unroll
        for (int k = 0; k < 8; ++k)
            if (v[k]) { idxb[bb] = (unsigned short)(j0 + k); bb++; }
        if (t == 255) cnt[b] = cb;
    }

    if (t == 0) {
        float tot = wsum[0] + wsum[1] + wsum[2] + wsum[3];
        float d = rsqrtf(1.f + tot);
        dis_o[row]  = d;
        rs[row]     = e * d;
        rself[row]  = e * d * d;
    }
}

// ---------------- K3: compacted transpose: yc8[b,d,k] = fp8(dis[idx_k] * xb[idx_k, d]) ----------------
__global__ __launch_bounds__(256) void k_yt(const unsigned short* __restrict__ xb,
                                            const float* __restrict__ dis,
                                            const unsigned short* __restrict__ idx,
                                            const int* __restrict__ cnt,
                                            unsigned char* __restrict__ yc8,
                                            int L, int D) {
    int b = blockIdx.z;
    int kb = blockIdx.x << 6;
    int db = blockIdx.y << 6;
    int cb = cnt[b];
    if (kb >= cb) return;
    __shared__ float tile[64][65];
    int t = threadIdx.x;
    int kk = t >> 2, c4 = (t & 3) << 4;
    int kg = kb + kk;
    if (kg < cb) {
        int ol = idx[(size_t)b * L + kg];
        float dl = dis[(size_t)b * L + ol];
        const unsigned short* xp = xb + ((size_t)b * L + ol) * D + db + c4;
        uint4 h0 = *(const uint4*)(xp);
        uint4 h1 = *(const uint4*)(xp + 8);
        unsigned hv[8] = {h0.x, h0.y, h0.z, h0.w, h1.x, h1.y, h1.z, h1.w};
        #pragma unroll
        for (int k = 0; k < 8; ++k) {
            tile[kk][c4 + 2 * k + 0] = bf2f((unsigned short)(hv[k] & 0xffffu)) * dl;
            tile[kk][c4 + 2 * k + 1] = bf2f((unsigned short)(hv[k] >> 16)) * dl;
        }
    } else {
        #pragma unroll
        for (int k = 0; k < 16; ++k) tile[kk][c4 + k] = 0.f;
    }
    __syncthreads();
    int dr = t >> 2, k0 = (t & 3) << 4;
    unsigned char* op = yc8 + ((size_t)b * D + db + dr) * L + kb + k0;
    uint4 o;
    o.x = pk2_fp8(tile[k0 + 0][dr],  tile[k0 + 1][dr])  | (pk2_fp8(tile[k0 + 2][dr],  tile[k0 + 3][dr])  << 16);
    o.y = pk2_fp8(tile[k0 + 4][dr],  tile[k0 + 5][dr])  | (pk2_fp8(tile[k0 + 6][dr],  tile[k0 + 7][dr])  << 16);
    o.z = pk2_fp8(tile[k0 + 8][dr],  tile[k0 + 9][dr])  | (pk2_fp8(tile[k0 + 10][dr], tile[k0 + 11][dr]) << 16);
    o.w = pk2_fp8(tile[k0 + 12][dr], tile[k0 + 13][dr]) | (pk2_fp8(tile[k0 + 14][dr], tile[k0 + 15][dr]) << 16);
    *(uint4*)(op) = o;
}

// ---------------- K4: compacted fp8 GEMM: agg8[idx_i] = fp8(rs_i*(amc8 @ yc8) + rself_i*x) ----------------
// BM=32, BN=128, BK=64; 4 waves of 16x64; ~1024 active blocks = 4/CU.
__global__ __launch_bounds__(256) void k_aggmm(
    const unsigned char* __restrict__ amc8,
    const unsigned char* __restrict__ yc8,
    const unsigned short* __restrict__ xb,
    const float* __restrict__ rs,
    const float* __restrict__ rself,
    const unsigned short* __restrict__ idx,
    const int* __restrict__ cnt,
    unsigned char* __restrict__ agg8,
    int L, int D)
{
    __shared__ __align__(16) unsigned char As[32 * 64];     // 2KB
    __shared__ __align__(16) unsigned char Bs[128 * 64];    // 8KB
    int bid = blockIdx.x;
    int wid = (bid & 7) * 256 + (bid >> 3);  // 2048 = 8*256, bijective; one batch per XCD
    int b   = wid >> 8;
    int t6  = wid & 255;
    int brow = (t6 >> 2) << 5;               // compacted row base (32-row tiles)
    int bcol = (t6 & 3) << 7;

    int Mc = cnt[b];
    if (brow >= Mc) return;                  // uniform early-exit
    int Kc = (Mc + 63) & ~63;

    int t = threadIdx.x;
    int lane = t & 63;
    int w = t >> 6;
    int wr = ((w >> 1) & 1) << 4;            // 0 or 16
    int wc = (w & 1) << 6;                   // 0 or 64

    const unsigned char* amb = amc8 + ((size_t)b * L + brow) * L;
    const unsigned char* yb  = yc8 + ((size_t)b * D + bcol) * L;
    const unsigned short* idxb = idx + (size_t)b * L;

    int r4 = t >> 2;                         // 0..63
    int c4 = t & 3;

    f32x4 acc[4];
    #pragma unroll
    for (int j = 0; j < 4; ++j) acc[j] = (f32x4){0.f, 0.f, 0.f, 0.f};

    const int lane15 = lane & 15;
    const int k8 = (lane >> 4) << 3;         // 8B k-chunk per lane

    for (int kc = 0; kc < Kc; kc += 64) {
        if (t < 128) {                       // A: 32 rows x 64B (dest = t*16, lane-linear)
            int rowa = t >> 2;
            int sc = c4 ^ (rowa & 3);        // pre-swizzled source, linear LDS dest
            gl_lds16(amb + (size_t)rowa * L + kc + sc * 16, As + t * 16);
        }
        #pragma unroll
        for (int q = 0; q < 2; ++q) {        // B: 128 rows x 64B; 2 issues
            int rowb = (q << 6) + r4;
            int sc = c4 ^ (rowb & 3);
            gl_lds16(yb + (size_t)rowb * L + kc + sc * 16, Bs + rowb * 64 + c4 * 16);
        }
        asm volatile("s_waitcnt vmcnt(0)" ::: "memory");
        __syncthreads();
        #pragma unroll
        for (int kk = 0; kk < 2; ++kk) {
            i64b af, bg[4];
            {
                int ar = wr + lane15;
                af = *(const i64b*)(As + ar * 64 + (((kk << 5) + k8) ^ ((ar & 3) << 4)));
            }
            #pragma unroll
            for (int f = 0; f < 4; ++f) {
                int br = wc + (f << 4) + lane15;
                bg[f] = *(const i64b*)(Bs + br * 64 + (((kk << 5) + k8) ^ ((br & 3) << 4)));
            }
            #pragma unroll
            for (int fn = 0; fn < 4; ++fn)
                acc[fn] = __builtin_amdgcn_mfma_f32_16x16x32_fp8_fp8(af, bg[fn], acc[fn], 0, 0, 0);
        }
        __syncthreads();
    }

    int col = lane15;
    int r0 = (lane >> 4) << 2;
    size_t bL = (size_t)b * L;
    #pragma unroll
    for (int j = 0; j < 4; ++j) {
        int rcmp = brow + wr + r0 + j;
        if (rcmp < Mc) {
            int gi = idxb[rcmp];
            float rsi = rs[bL + gi];
            float rfi = rself[bL + gi];
            const unsigned short* xrow = xb + (bL + gi) * (size_t)D;
            unsigned char* orow = agg8 + (bL + gi) * (size_t)D;
            #pragma unroll
            for (int fn = 0; fn < 4; ++fn) {
                int gd = bcol + wc + (fn << 4) + col;
                float v = rsi * acc[fn][j] + rfi * bf2f(xrow[gd]);
                orow[gd] = cv_fp8(v);
            }
        }
    }
}

// ---------------- K5: out = LN(x + relu(agg8 @ W8^T + b) * D^-0.5)  (fp8 MFMA, BM=32 x BN=512) ----------------
__global__ __launch_bounds__(256) void k_linln(
    const unsigned char* __restrict__ agg8,
    const unsigned char* __restrict__ W8,
    const float* __restrict__ bias,
    const unsigned short* __restrict__ xb,
    const float* __restrict__ lnw,
    const float* __restrict__ lnb,
    float* __restrict__ out)
{
    const int D = 512;
    __shared__ __align__(16) unsigned char As[32 * 64];     // 2KB
    __shared__ __align__(16) unsigned char Bs[512 * 64];    // 32KB
    __shared__ float psum[32][4], psq[32][4];

    int i0 = blockIdx.x << 5;
    int t = threadIdx.x;
    int lane = t & 63;
    int w = t >> 6;
    int wcol = w << 7;

    int r4 = t >> 2;                 // 0..63
    int c4 = t & 3;

    f32x4 acc[2][8];
    #pragma unroll
    for (int i = 0; i < 2; ++i)
        #pragma unroll
        for (int j = 0; j < 8; ++j)
            acc[i][j] = (f32x4){0.f, 0.f, 0.f, 0.f};

    const int lane15 = lane & 15;
    const int k8 = (lane >> 4) << 3;

    for (int kc = 0; kc < D; kc += 64) {
        if (t < 128) {               // A: 32 rows x 64B; waves 0-1 (dest = t*16, lane-linear)
            int row = t >> 2;        // 0..31
            int sc = c4 ^ (row & 3);
            gl_lds16(agg8 + (size_t)(i0 + row) * D + kc + sc * 16, As + t * 16);
        }
        #pragma unroll
        for (int q = 0; q < 8; ++q) {    // B: 512 rows x 64B; 8 issues (dest lane-linear)
            int row = (q << 6) + r4;
            int sc = c4 ^ (row & 3);
            gl_lds16(W8 + (size_t)row * D + kc + sc * 16, Bs + row * 64 + c4 * 16);
        }
        asm volatile("s_waitcnt vmcnt(0)" ::: "memory");
        __syncthreads();
        #pragma unroll
        for (int kk = 0; kk < 2; ++kk) {
            i64b af[2], bg[8];
            #pragma unroll
            for (int f = 0; f < 2; ++f) {
                int ar = (f << 4) + lane15;
                af[f] = *(const i64b*)(As + ar * 64 + (((kk << 5) + k8) ^ ((ar & 3) << 4)));
            }
            #pragma unroll
            for (int f = 0; f < 8; ++f) {
                int br = wcol + (f << 4) + lane15;
                bg[f] = *(const i64b*)(Bs + br * 64 + (((kk << 5) + k8) ^ ((br & 3) << 4)));
            }
            #pragma unroll
            for (int fm = 0; fm < 2; ++fm)
                #pragma unroll
                for (int fn = 0; fn < 8; ++fn)
                    acc[fm][fn] = __builtin_amdgcn_mfma_f32_16x16x32_fp8_fp8(af[fm], bg[fn], acc[fm][fn], 0, 0, 0);
        }
        __syncthreads();
    }

    const float scale = 0.044194173824159216f;   // 512^-0.5
    float bi[8], lw[8], lb[8];
    #pragma unroll
    for (int fn = 0; fn < 8; ++fn) {
        int colg = wcol + (fn << 4) + lane15;
        bi[fn] = bias[colg];
        lw[fn] = lnw[colg];
        lb[fn] = lnb[colg];
    }
    int r0 = (lane >> 4) << 2;
    #pragma unroll
    for (int fm = 0; fm < 2; ++fm) {
        #pragma unroll
        for (int j = 0; j < 4; ++j) {
            int r = (fm << 4) + r0 + j;
            const unsigned short* xrow = xb + (size_t)(i0 + r) * D;
            float s = 0.f, q = 0.f;
            #pragma unroll
            for (int fn = 0; fn < 8; ++fn) {
                int colg = wcol + (fn << 4) + lane15;
                float v = fmaxf(acc[fm][fn][j] + bi[fn], 0.f) * scale + bf2f(xrow[colg]);
                acc[fm][fn][j] = v;
                s += v;
                q += v * v;
            }
            #pragma unroll
            for (int m = 1; m < 16; m <<= 1) {
                s += __shfl_xor(s, m);
                q += __shfl_xor(q, m);
            }
            if (lane15 == 0) { psum[r][w] = s; psq[r][w] = q; }
        }
    }
    __syncthreads();
    #pragma unroll
    for (int fm = 0; fm < 2; ++fm) {
        #pragma unroll
        for (int j = 0; j < 4; ++j) {
            int r = (fm << 4) + r0 + j;
            float s = psum[r][0] + psum[r][1] + psum[r][2] + psum[r][3];
            float q = psq[r][0] + psq[r][1] + psq[r][2] + psq[r][3];
            float mu = s * (1.f / 512.f);
            float var = q * (1.f / 512.f) - mu * mu;
            float rstd = rsqrtf(var + LN_EPS);
            float* orow = out + (size_t)(i0 + r) * D;
            #pragma unroll
            for (int fn = 0; fn < 8; ++fn) {
                int colg = wcol + (fn << 4) + lane15;
                orow[colg] = lw[fn] * (acc[fm][fn][j] - mu) * rstd + lb[fn];
            }
        }
    }
}

extern "C" void kernel_launch(void* const* d_in, const int* in_sizes, int n_in,
                              void* d_out, int out_size, void* d_ws, size_t ws_size,
                              hipStream_t stream) {
    const float* x    = (const float*)d_in[0];
    const float* adj  = (const float*)d_in[1];
    const int*   pm   = (const int*)d_in[2];
    const float* W    = (const float*)d_in[3];
    const float* bias = (const float*)d_in[4];
    const float* lnw  = (const float*)d_in[5];
    const float* lnb  = (const float*)d_in[6];
    const float* ew   = (const float*)d_in[7];

    int BL = in_sizes[2];                 // B*L = 16384
    int L  = in_sizes[1] / BL;            // 2048
    int B  = BL / L;                      // 8
    int D  = in_sizes[0] / BL;            // 512

    char* ws = (char*)d_ws;
    size_t off = 0;
    float* dis   = (float*)(ws + off); off += (size_t)BL * 4;
    float* rs    = (float*)(ws + off); off += (size_t)BL * 4;
    float* rself = (float*)(ws + off); off += (size_t)BL * 4;
    unsigned short* idx = (unsigned short*)(ws + off); off += (size_t)BL * 2;
    int* cnt = (int*)(ws + off); off += 64;
    unsigned char* amc8 = (unsigned char*)(ws + off); off += (size_t)BL * L;
    unsigned char* yc8  = (unsigned char*)(ws + off); off += (size_t)BL * D;
    unsigned char* W8   = (unsigned char*)(ws + off); off += (size_t)D * D;
    unsigned char* agg8 = (unsigned char*)(ws + off); off += (size_t)BL * D;
    unsigned short* xb  = (unsigned short*)(ws + off); off += (size_t)BL * D * 2;

    float* out = (float*)d_out;
    int nx = (BL * D) / (256 * 8);        // 4096 xb data blocks
    int nw = (D * D) / (256 * 16);        // 64 W-convert blocks

    k_degxb<<<BL + nx + nw, 256, 0, stream>>>(adj, pm, ew, W, cnt, idx,
                                              dis, rs, rself, amc8, x, xb, agg8, W8, L, BL, nx);
    k_yt<<<dim3(L / 64, D / 64, B), 256, 0, stream>>>(xb, dis, idx, cnt, yc8, L, D);
    k_aggmm<<<B * (L / 32) * (D / 128), 256, 0, stream>>>(amc8, yc8, xb, rs, rself, idx, cnt, agg8, L, D);
    k_linln<<<BL / 32, 256, 0, stream>>>(agg8, W8, bias, xb, lnw, lnb, out);
}

// Round 13
// 84.383 us; speedup vs baseline: 1.0151x; 1.0151x over previous
//
#include <hip/hip_runtime.h>

#define LN_EPS 1e-5f

typedef __attribute__((ext_vector_type(8))) short s16x8;
typedef __attribute__((ext_vector_type(4))) float f32x4;
typedef long long i64b;

__device__ inline unsigned int pk_bf16(float a, float b) {
    unsigned ua = __builtin_bit_cast(unsigned, a);
    unsigned ub = __builtin_bit_cast(unsigned, b);
    ua += 0x7fffu + ((ua >> 16) & 1u);
    ub += 0x7fffu + ((ub >> 16) & 1u);
    return (ua >> 16) | (ub & 0xffff0000u);
}
__device__ inline float bf2f(unsigned short h) {
    unsigned u = ((unsigned)h) << 16;
    return __builtin_bit_cast(float, u);
}
__device__ inline unsigned pk2_fp8(float a, float b) {   // 2 fp8 e4m3 in bits[15:0]
    return (unsigned)__builtin_amdgcn_cvt_pk_fp8_f32(a, b, 0, false) & 0xffffu;
}
__device__ inline unsigned char cv_fp8(float a) {
    return (unsigned char)((unsigned)__builtin_amdgcn_cvt_pk_fp8_f32(a, 0.f, 0, false) & 0xffu);
}
__device__ inline void gl_lds16(const void* g, void* l) {
    __builtin_amdgcn_global_load_lds((const __attribute__((address_space(1))) void*)g,
                                     (__attribute__((address_space(3))) void*)l, 16, 0, 0);
}

// ---------------- K0: per-batch scan of valid mask -> pos, idx, cnt ----------------
__global__ __launch_bounds__(256) void k_scan(const int* __restrict__ pm,
                                              unsigned short* __restrict__ pos,
                                              unsigned short* __restrict__ idx,
                                              int* __restrict__ cnt, int L) {
    int b = blockIdx.x, t = threadIdx.x;
    const int* pmb = pm + (size_t)b * L;
    int j0 = t * 8;
    int v[8]; int s = 0;
    #pragma unroll
    for (int k = 0; k < 8; ++k) { v[k] = (pmb[j0 + k] == 0) ? 1 : 0; s += v[k]; }
    __shared__ int ps[256];
    ps[t] = s;
    __syncthreads();
    for (int off = 1; off < 256; off <<= 1) {
        int val = (t >= off) ? ps[t - off] : 0;
        __syncthreads();
        ps[t] += val;
        __syncthreads();
    }
    int base = ps[t] - s;   // exclusive prefix
    unsigned short* posb = pos + (size_t)b * L;
    unsigned short* idxb = idx + (size_t)b * L;
    #pragma unroll
    for (int k = 0; k < 8; ++k) {
        posb[j0 + k] = (unsigned short)base;
        if (v[k]) { idxb[base] = (unsigned short)(j0 + k); base++; }
    }
    if (t == 255) cnt[b] = ps[255];
}

// ---------------- K1: merged degree+amc(fp8) | xb bf16 + agg8-padded | W->W8 ----------------
__global__ __launch_bounds__(256) void k_degxb(const float* __restrict__ adj,
                                               const int* __restrict__ pm,
                                               const float* __restrict__ ew,
                                               const float* __restrict__ W,
                                               const unsigned short* __restrict__ pos,
                                               const int* __restrict__ cnt,
                                               float* __restrict__ dis_o,
                                               float* __restrict__ rs,
                                               float* __restrict__ rself,
                                               unsigned char* __restrict__ amc8,
                                               const float* __restrict__ x,
                                               unsigned short* __restrict__ xb,
                                               unsigned char* __restrict__ agg8,
                                               unsigned char* __restrict__ W8,
                                               int L, int nd, int nx) {
    const int D = 512;
    int bid = blockIdx.x;
    int t = threadIdx.x;
    float e = ew[0];
    if (bid >= nd) {
        int sub = bid - nd;
        if (sub >= nx) {                // W -> fp8 (64 blocks x 256 thr x 16 elems)
            int i = ((sub - nx) * 256 + t) * 16;
            uint4 o;
            float4 v0 = *(const float4*)(W + i);
            float4 v1 = *(const float4*)(W + i + 4);
            float4 v2 = *(const float4*)(W + i + 8);
            float4 v3 = *(const float4*)(W + i + 12);
            o.x = pk2_fp8(v0.x, v0.y) | (pk2_fp8(v0.z, v0.w) << 16);
            o.y = pk2_fp8(v1.x, v1.y) | (pk2_fp8(v1.z, v1.w) << 16);
            o.z = pk2_fp8(v2.x, v2.y) | (pk2_fp8(v2.z, v2.w) << 16);
            o.w = pk2_fp8(v3.x, v3.y) | (pk2_fp8(v3.z, v3.w) << 16);
            *(uint4*)(W8 + i) = o;
            return;
        }
        // xb = bf16(x); agg8 = fp8(e*x) for padded rows
        int gid = sub * 256 + t;
        int row = gid >> 6;
        int co = (gid & 63) << 3;
        const float* xp = x + (size_t)row * D + co;
        float4 v0 = *(const float4*)(xp);
        float4 v1 = *(const float4*)(xp + 4);
        uint4 o;
        o.x = pk_bf16(v0.x, v0.y);
        o.y = pk_bf16(v0.z, v0.w);
        o.z = pk_bf16(v1.x, v1.y);
        o.w = pk_bf16(v1.z, v1.w);
        *(uint4*)(xb + (size_t)row * D + co) = o;
        if (pm[row] != 0) {
            uint2 oa;
            oa.x = pk2_fp8(e * v0.x, e * v0.y) | (pk2_fp8(e * v0.z, e * v0.w) << 16);
            oa.y = pk2_fp8(e * v1.x, e * v1.y) | (pk2_fp8(e * v1.z, e * v1.w) << 16);
            *(uint2*)(agg8 + (size_t)row * D + co) = oa;
        }
        return;
    }
    // degree + compacted fp8 adjacency row
    int row = bid;
    int b = row / L;
    int i = row - b * L;
    const int* pmb = pm + (size_t)b * L;
    if (pmb[i] != 0) {                  // padded row: deg = 1
        if (t == 0) { dis_o[row] = 1.f; rs[row] = 0.f; rself[row] = e; }
        return;
    }
    __shared__ __align__(16) unsigned char ls8[2048 + 16];
    __shared__ float wsum[4];
    const float* arow = adj + (size_t)row * L;
    const unsigned short* posb = pos + (size_t)b * L;
    int rloc = posb[i];
    int cb = cnt[b];
    int kcap = (cb + 63) & ~63;

    for (int k = cb + t; k < kcap; k += 256) ls8[k] = 0;

    int j0 = t * 8;
    float4 a0 = *(const float4*)(arow + j0);
    float4 a1 = *(const float4*)(arow + j0 + 4);
    int4 p0 = *(const int4*)(pmb + j0);
    int4 p1 = *(const int4*)(pmb + j0 + 4);
    uint4 pv = *(const uint4*)(posb + j0);
    unsigned pc0 = pv.x & 0xffffu, pc1 = pv.x >> 16;
    unsigned pc2 = pv.y & 0xffffu, pc3 = pv.y >> 16;
    unsigned pc4 = pv.z & 0xffffu, pc5 = pv.z >> 16;
    unsigned pc6 = pv.w & 0xffffu, pc7 = pv.w >> 16;
    float m0 = p0.x == 0 ? a0.x : 0.f;
    float m1 = p0.y == 0 ? a0.y : 0.f;
    float m2 = p0.z == 0 ? a0.z : 0.f;
    float m3 = p0.w == 0 ? a0.w : 0.f;
    float m4 = p1.x == 0 ? a1.x : 0.f;
    float m5 = p1.y == 0 ? a1.y : 0.f;
    float m6 = p1.z == 0 ? a1.z : 0.f;
    float m7 = p1.w == 0 ? a1.w : 0.f;
    float s = ((m0 + m1) + (m2 + m3)) + ((m4 + m5) + (m6 + m7));
    if (p0.x == 0) ls8[pc0] = cv_fp8(m0);
    if (p0.y == 0) ls8[pc1] = cv_fp8(m1);
    if (p0.z == 0) ls8[pc2] = cv_fp8(m2);
    if (p0.w == 0) ls8[pc3] = cv_fp8(m3);
    if (p1.x == 0) ls8[pc4] = cv_fp8(m4);
    if (p1.y == 0) ls8[pc5] = cv_fp8(m5);
    if (p1.z == 0) ls8[pc6] = cv_fp8(m6);
    if (p1.w == 0) ls8[pc7] = cv_fp8(m7);

    #pragma unroll
    for (int off = 32; off; off >>= 1) s += __shfl_down(s, off);
    if ((t & 63) == 0) wsum[t >> 6] = s;
    __syncthreads();

    unsigned char* amrow = amc8 + ((size_t)b * L + rloc) * L;
    int j0b = t * 8;
    if (j0b < kcap) *(uint2*)(amrow + j0b) = *(const uint2*)(ls8 + j0b);

    if (t == 0) {
        float tot = wsum[0] + wsum[1] + wsum[2] + wsum[3];
        float d = rsqrtf(1.f + tot);
        dis_o[row]  = d;
        rs[row]     = e * d;
        rself[row]  = e * d * d;
    }
}

// ---------------- K3: compacted transpose: yc8[b,d,k] = fp8(dis[idx_k] * xb[idx_k, d]) ----------------
__global__ __launch_bounds__(256) void k_yt(const unsigned short* __restrict__ xb,
                                            const float* __restrict__ dis,
                                            const unsigned short* __restrict__ idx,
                                            const int* __restrict__ cnt,
                                            unsigned char* __restrict__ yc8,
                                            int L, int D) {
    int b = blockIdx.z;
    int kb = blockIdx.x << 6;
    int db = blockIdx.y << 6;
    int cb = cnt[b];
    if (kb >= cb) return;
    __shared__ float tile[64][65];
    int t = threadIdx.x;
    int kk = t >> 2, c4 = (t & 3) << 4;
    int kg = kb + kk;
    if (kg < cb) {
        int ol = idx[(size_t)b * L + kg];
        float dl = dis[(size_t)b * L + ol];
        const unsigned short* xp = xb + ((size_t)b * L + ol) * D + db + c4;
        uint4 h0 = *(const uint4*)(xp);
        uint4 h1 = *(const uint4*)(xp + 8);
        unsigned hv[8] = {h0.x, h0.y, h0.z, h0.w, h1.x, h1.y, h1.z, h1.w};
        #pragma unroll
        for (int k = 0; k < 8; ++k) {
            tile[kk][c4 + 2 * k + 0] = bf2f((unsigned short)(hv[k] & 0xffffu)) * dl;
            tile[kk][c4 + 2 * k + 1] = bf2f((unsigned short)(hv[k] >> 16)) * dl;
        }
    } else {
        #pragma unroll
        for (int k = 0; k < 16; ++k) tile[kk][c4 + k] = 0.f;
    }
    __syncthreads();
    int dr = t >> 2, k0 = (t & 3) << 4;
    unsigned char* op = yc8 + ((size_t)b * D + db + dr) * L + kb + k0;
    uint4 o;
    o.x = pk2_fp8(tile[k0 + 0][dr],  tile[k0 + 1][dr])  | (pk2_fp8(tile[k0 + 2][dr],  tile[k0 + 3][dr])  << 16);
    o.y = pk2_fp8(tile[k0 + 4][dr],  tile[k0 + 5][dr])  | (pk2_fp8(tile[k0 + 6][dr],  tile[k0 + 7][dr])  << 16);
    o.z = pk2_fp8(tile[k0 + 8][dr],  tile[k0 + 9][dr])  | (pk2_fp8(tile[k0 + 10][dr], tile[k0 + 11][dr]) << 16);
    o.w = pk2_fp8(tile[k0 + 12][dr], tile[k0 + 13][dr]) | (pk2_fp8(tile[k0 + 14][dr], tile[k0 + 15][dr]) << 16);
    *(uint4*)(op) = o;
}

// ---------------- K4: compacted fp8 GEMM: agg8[idx_i] = fp8(rs_i*(amc8 @ yc8) + rself_i*x) ----------------
__global__ __launch_bounds__(256) void k_aggmm(
    const unsigned char* __restrict__ amc8,
    const unsigned char* __restrict__ yc8,
    const unsigned short* __restrict__ xb,
    const float* __restrict__ rs,
    const float* __restrict__ rself,
    const unsigned short* __restrict__ idx,
    const int* __restrict__ cnt,
    unsigned char* __restrict__ agg8,
    int L, int D)
{
    __shared__ __align__(16) unsigned char As[64 * 64];     // 4KB
    __shared__ __align__(16) unsigned char Bs[128 * 64];    // 8KB
    int bid = blockIdx.x;
    int wid = (bid & 7) * 128 + (bid >> 3);  // 1024 = 8*128, bijective; one batch per XCD
    int b   = wid >> 7;
    int t6  = wid & 127;
    int brow = (t6 >> 2) << 6;               // compacted row base
    int bcol = (t6 & 3) << 7;

    int Mc = cnt[b];
    if (brow >= Mc) return;                  // uniform early-exit
    int Kc = (Mc + 63) & ~63;

    int t = threadIdx.x;
    int lane = t & 63;
    int w = t >> 6;
    int wr = ((w >> 1) & 1) << 5;            // 0 or 32
    int wc = (w & 1) << 6;                   // 0 or 64

    const unsigned char* amb = amc8 + ((size_t)b * L + brow) * L;
    const unsigned char* yb  = yc8 + ((size_t)b * D + bcol) * L;
    const unsigned short* idxb = idx + (size_t)b * L;

    int r4 = t >> 2;                         // 0..63
    int c4 = t & 3;

    f32x4 acc[2][4];
    #pragma unroll
    for (int i = 0; i < 2; ++i)
        #pragma unroll
        for (int j = 0; j < 4; ++j)
            acc[i][j] = (f32x4){0.f, 0.f, 0.f, 0.f};

    const int lane15 = lane & 15;
    const int k8 = (lane >> 4) << 3;         // 8B k-chunk per lane

    for (int kc = 0; kc < Kc; kc += 64) {
        {   // A: 64 rows x 64B; one 16B issue per thread (dest = t*16, lane-linear)
            int sc = c4 ^ (r4 & 3);          // pre-swizzled source, linear LDS dest
            gl_lds16(amb + (size_t)r4 * L + kc + sc * 16, As + r4 * 64 + c4 * 16);
        }
        #pragma unroll
        for (int q = 0; q < 2; ++q) {        // B: 128 rows x 64B; 2 issues
            int row = (q << 6) + r4;
            int sc = c4 ^ (row & 3);
            gl_lds16(yb + (size_t)row * L + kc + sc * 16, Bs + row * 64 + c4 * 16);
        }
        asm volatile("s_waitcnt vmcnt(0)" ::: "memory");
        __syncthreads();
        #pragma unroll
        for (int kk = 0; kk < 2; ++kk) {
            i64b af[2], bg[4];
            #pragma unroll
            for (int f = 0; f < 2; ++f) {
                int ar = wr + (f << 4) + lane15;
                af[f] = *(const i64b*)(As + ar * 64 + (((kk << 5) + k8) ^ ((ar & 3) << 4)));
            }
            #pragma unroll
            for (int f = 0; f < 4; ++f) {
                int br = wc + (f << 4) + lane15;
                bg[f] = *(const i64b*)(Bs + br * 64 + (((kk << 5) + k8) ^ ((br & 3) << 4)));
            }
            #pragma unroll
            for (int fm = 0; fm < 2; ++fm)
                #pragma unroll
                for (int fn = 0; fn < 4; ++fn)
                    acc[fm][fn] = __builtin_amdgcn_mfma_f32_16x16x32_fp8_fp8(af[fm], bg[fn], acc[fm][fn], 0, 0, 0);
        }
        __syncthreads();
    }

    int col = lane15;
    int r0 = (lane >> 4) << 2;
    size_t bL = (size_t)b * L;
    #pragma unroll
    for (int fm = 0; fm < 2; ++fm) {
        #pragma unroll
        for (int j = 0; j < 4; ++j) {
            int rcmp = brow + wr + (fm << 4) + r0 + j;
            if (rcmp < Mc) {
                int gi = idxb[rcmp];
                float rsi = rs[bL + gi];
                float rfi = rself[bL + gi];
                const unsigned short* xrow = xb + (bL + gi) * (size_t)D;
                unsigned char* orow = agg8 + (bL + gi) * (size_t)D;
                #pragma unroll
                for (int fn = 0; fn < 4; ++fn) {
                    int gd = bcol + wc + (fn << 4) + col;
                    float v = rsi * acc[fm][fn][j] + rfi * bf2f(xrow[gd]);
                    orow[gd] = cv_fp8(v);
                }
            }
        }
    }
}

// ---------------- K5: out = LN(x + relu(agg8 @ W8^T + b) * D^-0.5)  (fp8 MFMA, BM=32 x BN=512) ----------------
__global__ __launch_bounds__(256) void k_linln(
    const unsigned char* __restrict__ agg8,
    const unsigned char* __restrict__ W8,
    const float* __restrict__ bias,
    const unsigned short* __restrict__ xb,
    const float* __restrict__ lnw,
    const float* __restrict__ lnb,
    float* __restrict__ out)
{
    const int D = 512;
    __shared__ __align__(16) unsigned char As[32 * 64];     // 2KB
    __shared__ __align__(16) unsigned char Bs[512 * 64];    // 32KB
    __shared__ float psum[32][4], psq[32][4];

    int i0 = blockIdx.x << 5;
    int t = threadIdx.x;
    int lane = t & 63;
    int w = t >> 6;
    int wcol = w << 7;

    int r4 = t >> 2;                 // 0..63
    int c4 = t & 3;

    f32x4 acc[2][8];
    #pragma unroll
    for (int i = 0; i < 2; ++i)
        #pragma unroll
        for (int j = 0; j < 8; ++j)
            acc[i][j] = (f32x4){0.f, 0.f, 0.f, 0.f};

    const int lane15 = lane & 15;
    const int k8 = (lane >> 4) << 3;

    for (int kc = 0; kc < D; kc += 64) {
        if (t < 128) {               // A: 32 rows x 64B; waves 0-1 (dest = t*16, lane-linear)
            int row = t >> 2;        // 0..31
            int sc = c4 ^ (row & 3);
            gl_lds16(agg8 + (size_t)(i0 + row) * D + kc + sc * 16, As + t * 16);
        }
        #pragma unroll
        for (int q = 0; q < 8; ++q) {    // B: 512 rows x 64B; 8 issues (dest lane-linear)
            int row = (q << 6) + r4;
            int sc = c4 ^ (row & 3);
            gl_lds16(W8 + (size_t)row * D + kc + sc * 16, Bs + row * 64 + c4 * 16);
        }
        asm volatile("s_waitcnt vmcnt(0)" ::: "memory");
        __syncthreads();
        #pragma unroll
        for (int kk = 0; kk < 2; ++kk) {
            i64b af[2], bg[8];
            #pragma unroll
            for (int f = 0; f < 2; ++f) {
                int ar = (f << 4) + lane15;
                af[f] = *(const i64b*)(As + ar * 64 + (((kk << 5) + k8) ^ ((ar & 3) << 4)));
            }
            #pragma unroll
            for (int f = 0; f < 8; ++f) {
                int br = wcol + (f << 4) + lane15;
                bg[f] = *(const i64b*)(Bs + br * 64 + (((kk << 5) + k8) ^ ((br & 3) << 4)));
            }
            #pragma unroll
            for (int fm = 0; fm < 2; ++fm)
                #pragma unroll
                for (int fn = 0; fn < 8; ++fn)
                    acc[fm][fn] = __builtin_amdgcn_mfma_f32_16x16x32_fp8_fp8(af[fm], bg[fn], acc[fm][fn], 0, 0, 0);
        }
        __syncthreads();
    }

    const float scale = 0.044194173824159216f;   // 512^-0.5
    float bi[8], lw[8], lb[8];
    #pragma unroll
    for (int fn = 0; fn < 8; ++fn) {
        int colg = wcol + (fn << 4) + lane15;
        bi[fn] = bias[colg];
        lw[fn] = lnw[colg];
        lb[fn] = lnb[colg];
    }
    int r0 = (lane >> 4) << 2;
    #pragma unroll
    for (int fm = 0; fm < 2; ++fm) {
        #pragma unroll
        for (int j = 0; j < 4; ++j) {
            int r = (fm << 4) + r0 + j;
            const unsigned short* xrow = xb + (size_t)(i0 + r) * D;
            float s = 0.f, q = 0.f;
            #pragma unroll
            for (int fn = 0; fn < 8; ++fn) {
                int colg = wcol + (fn << 4) + lane15;
                float v = fmaxf(acc[fm][fn][j] + bi[fn], 0.f) * scale + bf2f(xrow[colg]);
                acc[fm][fn][j] = v;
                s += v;
                q += v * v;
            }
            #pragma unroll
            for (int m = 1; m < 16; m <<= 1) {
                s += __shfl_xor(s, m);
                q += __shfl_xor(q, m);
            }
            if (lane15 == 0) { psum[r][w] = s; psq[r][w] = q; }
        }
    }
    __syncthreads();
    #pragma unroll
    for (int fm = 0; fm < 2; ++fm) {
        #pragma unroll
        for (int j = 0; j < 4; ++j) {
            int r = (fm << 4) + r0 + j;
            float s = psum[r][0] + psum[r][1] + psum[r][2] + psum[r][3];
            float q = psq[r][0] + psq[r][1] + psq[r][2] + psq[r][3];
            float mu = s * (1.f / 512.f);
            float var = q * (1.f / 512.f) - mu * mu;
            float rstd = rsqrtf(var + LN_EPS);
            float* orow = out + (size_t)(i0 + r) * D;
            #pragma unroll
            for (int fn = 0; fn < 8; ++fn) {
                int colg = wcol + (fn << 4) + lane15;
                orow[colg] = lw[fn] * (acc[fm][fn][j] - mu) * rstd + lb[fn];
            }
        }
    }
}

extern "C" void kernel_launch(void* const* d_in, const int* in_sizes, int n_in,
                              void* d_out, int out_size, void* d_ws, size_t ws_size,
                              hipStream_t stream) {
    const float* x    = (const float*)d_in[0];
    const float* adj  = (const float*)d_in[1];
    const int*   pm   = (const int*)d_in[2];
    const float* W    = (const float*)d_in[3];
    const float* bias = (const float*)d_in[4];
    const float* lnw  = (const float*)d_in[5];
    const float* lnb  = (const float*)d_in[6];
    const float* ew   = (const float*)d_in[7];

    int BL = in_sizes[2];                 // B*L = 16384
    int L  = in_sizes[1] / BL;            // 2048
    int B  = BL / L;                      // 8
    int D  = in_sizes[0] / BL;            // 512

    char* ws = (char*)d_ws;
    size_t off = 0;
    float* dis   = (float*)(ws + off); off += (size_t)BL * 4;
    float* rs    = (float*)(ws + off); off += (size_t)BL * 4;
    float* rself = (float*)(ws + off); off += (size_t)BL * 4;
    unsigned short* pos = (unsigned short*)(ws + off); off += (size_t)BL * 2;
    unsigned short* idx = (unsigned short*)(ws + off); off += (size_t)BL * 2;
    int* cnt = (int*)(ws + off); off += 64;
    unsigned char* amc8 = (unsigned char*)(ws + off); off += (size_t)BL * L;
    unsigned char* yc8  = (unsigned char*)(ws + off); off += (size_t)BL * D;
    unsigned char* W8   = (unsigned char*)(ws + off); off += (size_t)D * D;
    unsigned char* agg8 = (unsigned char*)(ws + off); off += (size_t)BL * D;
    unsigned short* xb  = (unsigned short*)(ws + off); off += (size_t)BL * D * 2;

    float* out = (float*)d_out;
    int nx = (BL * D) / (256 * 8);        // 4096 xb data blocks
    int nw = (D * D) / (256 * 16);        // 64 W-convert blocks

    k_scan<<<B, 256, 0, stream>>>(pm, pos, idx, cnt, L);
    k_degxb<<<BL + nx + nw, 256, 0, stream>>>(adj, pm, ew, W, pos, cnt,
                                              dis, rs, rself, amc8, x, xb, agg8, W8, L, BL, nx);
    k_yt<<<dim3(L / 64, D / 64, B), 256, 0, stream>>>(xb, dis, idx, cnt, yc8, L, D);
    k_aggmm<<<B * (L / 64) * (D / 128), 256, 0, stream>>>(amc8, yc8, xb, rs, rself, idx, cnt, agg8, L, D);
    k_linln<<<BL / 32, 256, 0, stream>>>(agg8, W8, bias, xb, lnw, lnb, out);
}